// Round 1
// baseline (1550.185 us; speedup 1.0000x reference)
//
#include <hip/hip_runtime.h>

#define BATCH 128

// ---------------------------------------------------------------------------
// Spline activation: act[0] = silu(x), act[1..8] = cubic B-spline bases
// Grid: g[i] = (i-3)*0.4 - 1.0, i = 0..11  (uniform, all constants fold)
// ---------------------------------------------------------------------------
__device__ __forceinline__ void spline_acts(float xv, float act[9]) {
    act[0] = xv * (1.0f / (1.0f + __expf(-xv)));  // silu
    float g[12];
#pragma unroll
    for (int i = 0; i < 12; ++i) g[i] = (float)(i - 3) * 0.4f - 1.0f;
    float bb[11];
#pragma unroll
    for (int c = 0; c < 11; ++c) bb[c] = (xv >= g[c] && xv < g[c + 1]) ? 1.0f : 0.0f;
#pragma unroll
    for (int k = 1; k <= 3; ++k) {
#pragma unroll
        for (int c = 0; c + k < 11; ++c) {
            // denominators are compile-time constants -> reciprocal-multiplied
            float left  = (xv - g[c]) * (1.0f / (g[c + k] - g[c])) * bb[c];
            float right = (g[c + k + 1] - xv) * (1.0f / (g[c + k + 1] - g[c + 1])) * bb[c + 1];
            bb[c] = left + right;
        }
    }
#pragma unroll
    for (int c = 0; c < 8; ++c) act[c + 1] = bb[c];
}

// ---------------------------------------------------------------------------
// Pack weights: wpack[f*9*O + j*O + o] = (j==0) ? bw[o,f] : sw[o,f,j-1]*sc[o,f]
// ---------------------------------------------------------------------------
__global__ void pack_weights(const float* __restrict__ bw, const float* __restrict__ sw,
                             const float* __restrict__ sc, float* __restrict__ wpack,
                             int F, int O) {
    int i = blockIdx.x * blockDim.x + threadIdx.x;
    int total = F * 9 * O;
    if (i >= total) return;
    int o = i % O;
    int j = (i / O) % 9;
    int f = i / (9 * O);
    float v;
    if (j == 0) v = bw[o * F + f];
    else        v = sw[(o * F + f) * 8 + (j - 1)] * sc[o * F + f];
    wpack[i] = v;
}

// ---------------------------------------------------------------------------
// Fused KAN conv: one thread per output pixel (b,h,w), computes all COUT.
// x: (B, CIN, H, W); out: (B, COUT, H, W). 3x3, pad 1, stride 1.
// Patch feature order = (cin, dh, dw) to match conv_general_dilated_patches.
// ---------------------------------------------------------------------------
template <int CIN, int COUT, int H, int W>
__global__ __launch_bounds__(256) void kan_conv_kernel(const float* __restrict__ x,
                                                       const float* __restrict__ wpack,
                                                       float* __restrict__ out) {
    int n = blockIdx.x * 256 + threadIdx.x;
    if (n >= BATCH * H * W) return;
    int w = n % W;
    int h = (n / W) % H;
    int b = n / (W * H);

    float acc[COUT];
#pragma unroll
    for (int o = 0; o < COUT; ++o) acc[o] = 0.0f;

    const float* xb = x + (size_t)b * CIN * H * W;
    for (int cin = 0; cin < CIN; ++cin) {
        const float* xc = xb + cin * H * W;
#pragma unroll
        for (int dh = 0; dh < 3; ++dh) {
            int hh = h + dh - 1;
#pragma unroll
            for (int dw = 0; dw < 3; ++dw) {
                int ww = w + dw - 1;
                float xv = (hh >= 0 && hh < H && ww >= 0 && ww < W) ? xc[hh * W + ww] : 0.0f;
                float act[9];
                spline_acts(xv, act);
                const float* wp = wpack + (size_t)(cin * 9 + dh * 3 + dw) * 9 * COUT;
#pragma unroll
                for (int j = 0; j < 9; ++j) {
#pragma unroll
                    for (int o = 0; o < COUT; ++o)
                        acc[o] += act[j] * wp[j * COUT + o];
                }
            }
        }
    }
    size_t obase = ((size_t)b * COUT) * H * W + (size_t)h * W + w;
#pragma unroll
    for (int o = 0; o < COUT; ++o) out[obase + (size_t)o * H * W] = acc[o];
}

// ---------------------------------------------------------------------------
// 2x2 max pool, stride 2. in: (B, C, H, W) -> out: (B, C, H/2, W/2)
// ---------------------------------------------------------------------------
__global__ void maxpool_kernel(const float* __restrict__ in, float* __restrict__ out,
                               int C, int H, int W, int total) {
    int i = blockIdx.x * blockDim.x + threadIdx.x;
    if (i >= total) return;
    int W2 = W / 2, H2 = H / 2;
    int w = i % W2;
    int h = (i / W2) % H2;
    int c = (i / (W2 * H2)) % C;
    int b = i / (W2 * H2 * C);
    const float* p = in + (((size_t)b * C + c) * H + 2 * h) * W + 2 * w;
    float m = fmaxf(fmaxf(p[0], p[1]), fmaxf(p[W], p[W + 1]));
    out[i] = m;
}

// ---------------------------------------------------------------------------
// Tiled fp32 GEMM: C[m,n] = sum_k A[m,k] * Wt[n,k] + bias[n], optional relu.
// 32x32 tile per block, 256 threads, each computes 2x2.
// ---------------------------------------------------------------------------
__global__ __launch_bounds__(256) void fc_kernel(const float* __restrict__ A,
                                                 const float* __restrict__ Wt,
                                                 const float* __restrict__ bias,
                                                 float* __restrict__ C,
                                                 int M, int N, int K, int relu) {
    __shared__ float As[32][33];
    __shared__ float Ws[32][33];
    int tx = threadIdx.x & 15, ty = threadIdx.x >> 4;
    int bm = blockIdx.y * 32, bn = blockIdx.x * 32;
    float acc00 = 0.f, acc01 = 0.f, acc10 = 0.f, acc11 = 0.f;
    for (int k0 = 0; k0 < K; k0 += 32) {
#pragma unroll
        for (int i = threadIdx.x; i < 32 * 32; i += 256) {
            int r = i >> 5, c = i & 31;
            As[r][c] = A[(size_t)(bm + r) * K + k0 + c];
            Ws[r][c] = Wt[(size_t)(bn + r) * K + k0 + c];
        }
        __syncthreads();
#pragma unroll
        for (int kk = 0; kk < 32; ++kk) {
            float a0 = As[ty][kk], a1 = As[ty + 16][kk];
            float w0 = Ws[tx][kk], w1 = Ws[tx + 16][kk];
            acc00 += a0 * w0; acc01 += a0 * w1;
            acc10 += a1 * w0; acc11 += a1 * w1;
        }
        __syncthreads();
    }
    int m0 = bm + ty, m1 = bm + ty + 16, n0 = bn + tx, n1 = bn + tx + 16;
    float b0 = bias[n0], b1 = bias[n1];
    float v00 = acc00 + b0, v01 = acc01 + b1, v10 = acc10 + b0, v11 = acc11 + b1;
    if (relu) {
        v00 = fmaxf(v00, 0.f); v01 = fmaxf(v01, 0.f);
        v10 = fmaxf(v10, 0.f); v11 = fmaxf(v11, 0.f);
    }
    C[(size_t)m0 * N + n0] = v00;
    C[(size_t)m0 * N + n1] = v01;
    C[(size_t)m1 * N + n0] = v10;
    C[(size_t)m1 * N + n1] = v11;
}

// Tiny final FC (M=128, N=10, K=1024): one thread per output.
__global__ void fc3_kernel(const float* __restrict__ A, const float* __restrict__ Wt,
                           const float* __restrict__ bias, float* __restrict__ C,
                           int M, int N, int K) {
    int i = blockIdx.x * blockDim.x + threadIdx.x;
    if (i >= M * N) return;
    int n = i % N, m = i / N;
    float s = bias[n];
    for (int k = 0; k < K; ++k) s += A[(size_t)m * K + k] * Wt[(size_t)n * K + k];
    C[i] = s;
}

// ---------------------------------------------------------------------------
extern "C" void kernel_launch(void* const* d_in, const int* in_sizes, int n_in,
                              void* d_out, int out_size, void* d_ws, size_t ws_size,
                              hipStream_t stream) {
    const float* x   = (const float*)d_in[0];
    const float* bw1 = (const float*)d_in[1];
    const float* sw1 = (const float*)d_in[2];
    const float* sc1 = (const float*)d_in[3];
    const float* bw2 = (const float*)d_in[4];
    const float* sw2 = (const float*)d_in[5];
    const float* sc2 = (const float*)d_in[6];
    const float* bw3 = (const float*)d_in[7];
    const float* sw3 = (const float*)d_in[8];
    const float* sc3 = (const float*)d_in[9];
    const float* bw4 = (const float*)d_in[10];
    const float* sw4 = (const float*)d_in[11];
    const float* sc4 = (const float*)d_in[12];
    const float* w1  = (const float*)d_in[13];
    const float* b1  = (const float*)d_in[14];
    const float* w2  = (const float*)d_in[15];
    const float* b2  = (const float*)d_in[16];
    const float* w3  = (const float*)d_in[17];
    const float* b3  = (const float*)d_in[18];

    float* ws  = (float*)d_ws;
    float* wp1 = ws;            // 27*9*4   = 972
    float* wp2 = wp1 + 972;     // 36*9*8   = 2592
    float* wp3 = wp2 + 2592;    // 72*9*16  = 10368
    float* wp4 = wp3 + 10368;   // 144*9*32 = 41472
    float* s1  = ws + 65536;    // 524288 floats (2 MB)
    float* s2  = s1 + 524288;   // 1048576 floats (4 MB)
    float* s3  = s2 + 1048576;  // 262144 floats (1 MB)
    // total ws use: (65536 + 524288 + 1048576 + 262144) * 4 B = 7.25 MB

    // weight packing
    pack_weights<<<(972 + 255) / 256, 256, 0, stream>>>(bw1, sw1, sc1, wp1, 27, 4);
    pack_weights<<<(2592 + 255) / 256, 256, 0, stream>>>(bw2, sw2, sc2, wp2, 36, 8);
    pack_weights<<<(10368 + 255) / 256, 256, 0, stream>>>(bw3, sw3, sc3, wp3, 72, 16);
    pack_weights<<<(41472 + 255) / 256, 256, 0, stream>>>(bw4, sw4, sc4, wp4, 144, 32);

    // conv1: x (128,3,32,32) -> s1 (128,4,32,32)
    kan_conv_kernel<3, 4, 32, 32><<<512, 256, 0, stream>>>(x, wp1, s1);
    // conv2: s1 -> s2 (128,8,32,32)
    kan_conv_kernel<4, 8, 32, 32><<<512, 256, 0, stream>>>(s1, wp2, s2);
    // pool1: s2 -> s3 (128,8,16,16)
    maxpool_kernel<<<(262144 + 255) / 256, 256, 0, stream>>>(s2, s3, 8, 32, 32, 262144);
    // conv3: s3 -> s1 (128,16,16,16)
    kan_conv_kernel<8, 16, 16, 16><<<128, 256, 0, stream>>>(s3, wp3, s1);
    // conv4: s1 -> s2 (128,32,16,16)
    kan_conv_kernel<16, 32, 16, 16><<<128, 256, 0, stream>>>(s1, wp4, s2);
    // pool2: s2 -> s3 (128,32,8,8) == flattened (128, 2048)
    maxpool_kernel<<<(262144 + 255) / 256, 256, 0, stream>>>(s2, s3, 32, 16, 16, 262144);
    // fc1: relu(s3 @ w1.T + b1) -> s1 (128,2048)
    {
        dim3 g(2048 / 32, 128 / 32);
        fc_kernel<<<g, 256, 0, stream>>>(s3, w1, b1, s1, 128, 2048, 2048, 1);
    }
    // fc2: relu(s1 @ w2.T + b2) -> s1+262144 (128,1024)
    {
        dim3 g(1024 / 32, 128 / 32);
        fc_kernel<<<g, 256, 0, stream>>>(s1, w2, b2, s1 + 262144, 128, 1024, 2048, 1);
    }
    // fc3: (128,1024) @ w3.T + b3 -> d_out (128,10)
    fc3_kernel<<<(1280 + 255) / 256, 256, 0, stream>>>(s1 + 262144, w3, b3, (float*)d_out,
                                                       128, 10, 1024);
}

// Round 2
// 636.521 us; speedup vs baseline: 2.4354x; 2.4354x over previous
//
#include <hip/hip_runtime.h>

#define BATCH 128

// ---------------------------------------------------------------------------
// Spline activation: act[0] = silu(x), act[1..8] = cubic B-spline bases
// Grid: g[i] = (i-3)*0.4 - 1.0, i = 0..11  (uniform, all constants fold)
// ---------------------------------------------------------------------------
__device__ __forceinline__ void spline_acts(float xv, float act[9]) {
    act[0] = xv * (1.0f / (1.0f + __expf(-xv)));  // silu
    float g[12];
#pragma unroll
    for (int i = 0; i < 12; ++i) g[i] = (float)(i - 3) * 0.4f - 1.0f;
    float bb[11];
#pragma unroll
    for (int c = 0; c < 11; ++c) bb[c] = (xv >= g[c] && xv < g[c + 1]) ? 1.0f : 0.0f;
#pragma unroll
    for (int k = 1; k <= 3; ++k) {
#pragma unroll
        for (int c = 0; c + k < 11; ++c) {
            float left  = (xv - g[c]) * (1.0f / (g[c + k] - g[c])) * bb[c];
            float right = (g[c + k + 1] - xv) * (1.0f / (g[c + k + 1] - g[c + 1])) * bb[c + 1];
            bb[c] = left + right;
        }
    }
#pragma unroll
    for (int c = 0; c < 8; ++c) act[c + 1] = bb[c];
}

// spline_acts(0.0f) — the activation vector of a zero-padded tap (constants).
// bases at x=0: nonzero at act[3..6] = {0.125/6, 0.575/1.2, 0.575/1.2, 0.125/6}
__device__ __constant__ float ZPAD[9] = {0.0f, 0.0f, 0.0f, 0.02083333333f,
                                         0.47916666667f, 0.47916666667f,
                                         0.02083333333f, 0.0f, 0.0f};

// ---------------------------------------------------------------------------
// Pack weights for all 4 layers into one kernel.
// wpack[f*9*O + j*O + o] = (j==0) ? bw[o,f] : sw[o,f,j-1]*sc[o,f]
// ---------------------------------------------------------------------------
__device__ __forceinline__ void pack_one(int i, const float* bw, const float* sw,
                                         const float* sc, float* out, int F, int O) {
    int o = i % O;
    int j = (i / O) % 9;
    int f = i / (9 * O);
    float v;
    if (j == 0) v = bw[o * F + f];
    else        v = sw[(o * F + f) * 8 + (j - 1)] * sc[o * F + f];
    out[i] = v;
}

__global__ void pack_all(const float* __restrict__ bw1, const float* __restrict__ sw1,
                         const float* __restrict__ sc1, const float* __restrict__ bw2,
                         const float* __restrict__ sw2, const float* __restrict__ sc2,
                         const float* __restrict__ bw3, const float* __restrict__ sw3,
                         const float* __restrict__ sc3, const float* __restrict__ bw4,
                         const float* __restrict__ sw4, const float* __restrict__ sc4,
                         float* __restrict__ ws) {
    int i = blockIdx.x * blockDim.x + threadIdx.x;
    // ranges: L1 [0,972) L2 [972,3564) L3 [3564,13932) L4 [13932,55404)
    if (i < 972)        pack_one(i,         bw1, sw1, sc1, ws,         27, 4);
    else if (i < 3564)  pack_one(i - 972,   bw2, sw2, sc2, ws + 972,   36, 8);
    else if (i < 13932) pack_one(i - 3564,  bw3, sw3, sc3, ws + 3564,  72, 16);
    else if (i < 55404) pack_one(i - 13932, bw4, sw4, sc4, ws + 13932, 144, 32);
}

// ---------------------------------------------------------------------------
// Spline expansion: x (BC, HW) -> SP (BC, 9, HW)
// ---------------------------------------------------------------------------
__global__ void spline_expand(const float* __restrict__ x, float* __restrict__ SP,
                              int HW, int total) {
    int i = blockIdx.x * blockDim.x + threadIdx.x;
    if (i >= total) return;
    int p = i % HW;
    int bc = i / HW;
    float a9[9];
    spline_acts(x[i], a9);
    float* ob = SP + (size_t)bc * 9 * HW + p;
#pragma unroll
    for (int j = 0; j < 9; ++j) ob[j * HW] = a9[j];
}

// ---------------------------------------------------------------------------
// Pool (2x2 max) + spline expansion: in (BC, H, W) -> SP (BC, 9, H/2, W/2)
// ---------------------------------------------------------------------------
__global__ void pool_spline(const float* __restrict__ in, float* __restrict__ SP,
                            int H, int W, int total) {
    int i = blockIdx.x * blockDim.x + threadIdx.x;
    if (i >= total) return;
    int W2 = W / 2, H2 = H / 2, HW2 = W2 * H2;
    int w = i % W2;
    int h = (i / W2) % H2;
    int bc = i / HW2;
    const float* p = in + ((size_t)bc * H + 2 * h) * W + 2 * w;
    float m = fmaxf(fmaxf(p[0], p[1]), fmaxf(p[W], p[W + 1]));
    float a9[9];
    spline_acts(m, a9);
    float* ob = SP + (size_t)bc * 9 * HW2 + h * W2 + w;
#pragma unroll
    for (int j = 0; j < 9; ++j) ob[j * HW2] = a9[j];
}

// ---------------------------------------------------------------------------
// Plain 2x2 max pool: in (BC, H, W) -> out (BC, H/2, W/2)
// ---------------------------------------------------------------------------
__global__ void maxpool_kernel(const float* __restrict__ in, float* __restrict__ out,
                               int H, int W, int total) {
    int i = blockIdx.x * blockDim.x + threadIdx.x;
    if (i >= total) return;
    int W2 = W / 2, H2 = H / 2, HW2 = W2 * H2;
    int w = i % W2;
    int h = (i / W2) % H2;
    int bc = i / HW2;
    const float* p = in + ((size_t)bc * H + 2 * h) * W + 2 * w;
    out[i] = fmaxf(fmaxf(p[0], p[1]), fmaxf(p[W], p[W + 1]));
}

// ---------------------------------------------------------------------------
// KAN conv over precomputed splines.
// SP: (B, CIN, 9, H, W). wp: [(cin*9+tap)*9+j][COUT]. blockIdx.y = cout group
// (CO channels each) -> weight addresses are block-uniform -> scalar loads.
// EPI=0: out raw (B, COUT, H, W). EPI=1: out = SP_next (B, COUT, 9, H, W).
// ---------------------------------------------------------------------------
template <int CIN, int COUT, int CO, int H, int W, int EPI>
__global__ __launch_bounds__(256) void conv_kernel(const float* __restrict__ SP,
                                                   const float* __restrict__ wp,
                                                   float* __restrict__ out) {
    constexpr int HW = H * W;
    int n = blockIdx.x * 256 + threadIdx.x;  // grid sized exactly: n < BATCH*HW
    const int o0 = blockIdx.y * CO;
    int w = n % W;
    int h = (n / W) % H;
    int b = n / HW;

    float acc[CO];
#pragma unroll
    for (int i = 0; i < CO; ++i) acc[i] = 0.0f;

    const float* spb = SP + (size_t)b * CIN * 9 * HW;
#pragma unroll 1
    for (int cin = 0; cin < CIN; ++cin) {
        const float* spc = spb + cin * 9 * HW;
#pragma unroll
        for (int dh = 0; dh < 3; ++dh) {
            int hh = h + dh - 1;
#pragma unroll
            for (int dw = 0; dw < 3; ++dw) {
                int ww = w + dw - 1;
                bool inb = ((unsigned)hh < (unsigned)H) && ((unsigned)ww < (unsigned)W);
                int off = inb ? hh * W + ww : 0;
                const float* wrow = wp + ((size_t)(cin * 9 + dh * 3 + dw) * 9) * COUT + o0;
#pragma unroll
                for (int j = 0; j < 9; ++j) {
                    float v = spc[j * HW + off];
                    float sj = inb ? v : ZPAD[j];
#pragma unroll
                    for (int co = 0; co < CO; ++co)
                        acc[co] = fmaf(sj, wrow[j * COUT + co], acc[co]);
                }
            }
        }
    }

    int p = h * W + w;
    if (EPI == 0) {
        float* ob = out + ((size_t)b * COUT + o0) * HW + p;
#pragma unroll
        for (int co = 0; co < CO; ++co) ob[(size_t)co * HW] = acc[co];
    } else {
#pragma unroll
        for (int co = 0; co < CO; ++co) {
            float a9[9];
            spline_acts(acc[co], a9);
            float* ob = out + ((size_t)(b * COUT + o0 + co) * 9) * HW + p;
#pragma unroll
            for (int j = 0; j < 9; ++j) ob[j * HW] = a9[j];
        }
    }
}

// ---------------------------------------------------------------------------
// Tiled fp32 GEMM: C[m,n] = sum_k A[m,k] * Wt[n,k] + bias[n], optional relu.
// ---------------------------------------------------------------------------
__global__ __launch_bounds__(256) void fc_kernel(const float* __restrict__ A,
                                                 const float* __restrict__ Wt,
                                                 const float* __restrict__ bias,
                                                 float* __restrict__ C,
                                                 int M, int N, int K, int relu) {
    __shared__ float As[32][33];
    __shared__ float Ws[32][33];
    int tx = threadIdx.x & 15, ty = threadIdx.x >> 4;
    int bm = blockIdx.y * 32, bn = blockIdx.x * 32;
    float acc00 = 0.f, acc01 = 0.f, acc10 = 0.f, acc11 = 0.f;
    for (int k0 = 0; k0 < K; k0 += 32) {
#pragma unroll
        for (int i = threadIdx.x; i < 32 * 32; i += 256) {
            int r = i >> 5, c = i & 31;
            As[r][c] = A[(size_t)(bm + r) * K + k0 + c];
            Ws[r][c] = Wt[(size_t)(bn + r) * K + k0 + c];
        }
        __syncthreads();
#pragma unroll
        for (int kk = 0; kk < 32; ++kk) {
            float a0 = As[ty][kk], a1 = As[ty + 16][kk];
            float w0 = Ws[tx][kk], w1 = Ws[tx + 16][kk];
            acc00 += a0 * w0; acc01 += a0 * w1;
            acc10 += a1 * w0; acc11 += a1 * w1;
        }
        __syncthreads();
    }
    int m0 = bm + ty, m1 = bm + ty + 16, n0 = bn + tx, n1 = bn + tx + 16;
    float b0 = bias[n0], b1 = bias[n1];
    float v00 = acc00 + b0, v01 = acc01 + b1, v10 = acc10 + b0, v11 = acc11 + b1;
    if (relu) {
        v00 = fmaxf(v00, 0.f); v01 = fmaxf(v01, 0.f);
        v10 = fmaxf(v10, 0.f); v11 = fmaxf(v11, 0.f);
    }
    C[(size_t)m0 * N + n0] = v00;
    C[(size_t)m0 * N + n1] = v01;
    C[(size_t)m1 * N + n0] = v10;
    C[(size_t)m1 * N + n1] = v11;
}

// Tiny final FC (M=128, N=10, K=1024)
__global__ void fc3_kernel(const float* __restrict__ A, const float* __restrict__ Wt,
                           const float* __restrict__ bias, float* __restrict__ C,
                           int M, int N, int K) {
    int i = blockIdx.x * blockDim.x + threadIdx.x;
    if (i >= M * N) return;
    int n = i % N, m = i / N;
    float s = bias[n];
    for (int k = 0; k < K; ++k) s += A[(size_t)m * K + k] * Wt[(size_t)n * K + k];
    C[i] = s;
}

// ---------------------------------------------------------------------------
extern "C" void kernel_launch(void* const* d_in, const int* in_sizes, int n_in,
                              void* d_out, int out_size, void* d_ws, size_t ws_size,
                              hipStream_t stream) {
    const float* x   = (const float*)d_in[0];
    const float* bw1 = (const float*)d_in[1];
    const float* sw1 = (const float*)d_in[2];
    const float* sc1 = (const float*)d_in[3];
    const float* bw2 = (const float*)d_in[4];
    const float* sw2 = (const float*)d_in[5];
    const float* sc2 = (const float*)d_in[6];
    const float* bw3 = (const float*)d_in[7];
    const float* sw3 = (const float*)d_in[8];
    const float* sc3 = (const float*)d_in[9];
    const float* bw4 = (const float*)d_in[10];
    const float* sw4 = (const float*)d_in[11];
    const float* sc4 = (const float*)d_in[12];
    const float* w1  = (const float*)d_in[13];
    const float* b1  = (const float*)d_in[14];
    const float* w2  = (const float*)d_in[15];
    const float* b2  = (const float*)d_in[16];
    const float* w3  = (const float*)d_in[17];
    const float* b3  = (const float*)d_in[18];

    float* ws  = (float*)d_ws;
    float* wp1 = ws;           // 27*9*4   @ [0,972)
    float* wp2 = ws + 972;     // 36*9*8   @ [972,3564)
    float* wp3 = ws + 3564;    // 72*9*16  @ [3564,13932)
    float* wp4 = ws + 13932;   // 144*9*32 @ [13932,55404)
    float* base = ws + 65536;
    // liveness-packed activation buffers (floats, relative to base):
    float* SP1    = base;              // 3,538,944  (B,3,9,32,32)
    float* SP2    = base + 3538944;    // 4,718,592  (B,4,9,32,32)
    float* out2   = base;              // 1,048,576  (B,8,32,32)   over dead SP1
    float* SP3    = base + 1048576;    // 2,359,296  (B,8,9,16,16)
    float* SP4    = base + 3407872;    // 4,718,592  (B,16,9,16,16)
    float* out4   = base;              // 1,048,576  (B,32,16,16)  over dead SP3-
    float* pooled = base + 1048576;    // 262,144    (B,2048)
    float* fc1o   = base + 1310720;    // 262,144
    float* fc2o   = base;              // 131,072
    // peak = (65536 + 8,257,536) * 4B = 33.3 MB

    pack_all<<<(55404 + 255) / 256, 256, 0, stream>>>(bw1, sw1, sc1, bw2, sw2, sc2,
                                                      bw3, sw3, sc3, bw4, sw4, sc4, ws);

    // spline of input x: (128*3, 1024) -> SP1
    spline_expand<<<1536, 256, 0, stream>>>(x, SP1, 1024, 393216);
    // conv1: SP1 -> SP2 (fused spline epilogue), 4 couts in 1 group
    conv_kernel<3, 4, 4, 32, 32, 1><<<dim3(512, 1), 256, 0, stream>>>(SP1, wp1, SP2);
    // conv2: SP2 -> out2 raw, 8 couts in 1 group
    conv_kernel<4, 8, 8, 32, 32, 0><<<dim3(512, 1), 256, 0, stream>>>(SP2, wp2, out2);
    // pool1 + spline: out2 (128*8,32,32) -> SP3
    pool_spline<<<1024, 256, 0, stream>>>(out2, SP3, 32, 32, 262144);
    // conv3: SP3 -> SP4 (fused spline), 16 couts in 2 groups of 8
    conv_kernel<8, 16, 8, 16, 16, 1><<<dim3(128, 2), 256, 0, stream>>>(SP3, wp3, SP4);
    // conv4: SP4 -> out4 raw, 32 couts in 4 groups of 8
    conv_kernel<16, 32, 8, 16, 16, 0><<<dim3(128, 4), 256, 0, stream>>>(SP4, wp4, out4);
    // pool2: out4 (128*32,16,16) -> pooled (B,2048)
    maxpool_kernel<<<1024, 256, 0, stream>>>(out4, pooled, 16, 16, 262144);
    // fc1: relu(pooled @ w1.T + b1)
    fc_kernel<<<dim3(64, 4), 256, 0, stream>>>(pooled, w1, b1, fc1o, 128, 2048, 2048, 1);
    // fc2: relu(fc1o @ w2.T + b2)
    fc_kernel<<<dim3(32, 4), 256, 0, stream>>>(fc1o, w2, b2, fc2o, 128, 1024, 2048, 1);
    // fc3
    fc3_kernel<<<5, 256, 0, stream>>>(fc2o, w3, b3, (float*)d_out, 128, 10, 1024);
}

// Round 3
// 287.547 us; speedup vs baseline: 5.3911x; 2.2136x over previous
//
#include <hip/hip_runtime.h>

#define BATCH 128

// ---------------------------------------------------------------------------
// Spline activation: act[0] = silu(x), act[1..8] = cubic B-spline bases
// Grid: g[i] = (i-3)*0.4 - 1.0, i = 0..11  (uniform, all constants fold)
// ---------------------------------------------------------------------------
__device__ __forceinline__ void spline_acts(float xv, float act[9]) {
    act[0] = xv * (1.0f / (1.0f + __expf(-xv)));  // silu
    float g[12];
#pragma unroll
    for (int i = 0; i < 12; ++i) g[i] = (float)(i - 3) * 0.4f - 1.0f;
    float bb[11];
#pragma unroll
    for (int c = 0; c < 11; ++c) bb[c] = (xv >= g[c] && xv < g[c + 1]) ? 1.0f : 0.0f;
#pragma unroll
    for (int k = 1; k <= 3; ++k) {
#pragma unroll
        for (int c = 0; c + k < 11; ++c) {
            float left  = (xv - g[c]) * (1.0f / (g[c + k] - g[c])) * bb[c];
            float right = (g[c + k + 1] - xv) * (1.0f / (g[c + k + 1] - g[c + 1])) * bb[c + 1];
            bb[c] = left + right;
        }
    }
#pragma unroll
    for (int c = 0; c < 8; ++c) act[c + 1] = bb[c];
}

// spline_acts(0.0f) — activation vector of a zero-padded tap (constants).
__device__ __constant__ float ZPAD[9] = {0.0f, 0.0f, 0.0f, 0.02083333333f,
                                         0.47916666667f, 0.47916666667f,
                                         0.02083333333f, 0.0f, 0.0f};

// ---------------------------------------------------------------------------
// Pack weights for all 4 layers into one kernel.
// wpack[f*9*O + j*O + o] = (j==0) ? bw[o,f] : sw[o,f,j-1]*sc[o,f]
// ---------------------------------------------------------------------------
__device__ __forceinline__ void pack_one(int i, const float* bw, const float* sw,
                                         const float* sc, float* out, int F, int O) {
    int o = i % O;
    int j = (i / O) % 9;
    int f = i / (9 * O);
    float v;
    if (j == 0) v = bw[o * F + f];
    else        v = sw[(o * F + f) * 8 + (j - 1)] * sc[o * F + f];
    out[i] = v;
}

__global__ void pack_all(const float* __restrict__ bw1, const float* __restrict__ sw1,
                         const float* __restrict__ sc1, const float* __restrict__ bw2,
                         const float* __restrict__ sw2, const float* __restrict__ sc2,
                         const float* __restrict__ bw3, const float* __restrict__ sw3,
                         const float* __restrict__ sc3, const float* __restrict__ bw4,
                         const float* __restrict__ sw4, const float* __restrict__ sc4,
                         float* __restrict__ ws) {
    int i = blockIdx.x * blockDim.x + threadIdx.x;
    if (i < 972)        pack_one(i,         bw1, sw1, sc1, ws,         27, 4);
    else if (i < 3564)  pack_one(i - 972,   bw2, sw2, sc2, ws + 972,   36, 8);
    else if (i < 13932) pack_one(i - 3564,  bw3, sw3, sc3, ws + 3564,  72, 16);
    else if (i < 55404) pack_one(i - 13932, bw4, sw4, sc4, ws + 13932, 144, 32);
}

// ---------------------------------------------------------------------------
// Spline expansion: x (BC, HW) -> SP (BC, 9, HW)
// ---------------------------------------------------------------------------
__global__ void spline_expand(const float* __restrict__ x, float* __restrict__ SP,
                              int HW, int total) {
    int i = blockIdx.x * blockDim.x + threadIdx.x;
    if (i >= total) return;
    int p = i % HW;
    int bc = i / HW;
    float a9[9];
    spline_acts(x[i], a9);
    float* ob = SP + (size_t)bc * 9 * HW + p;
#pragma unroll
    for (int j = 0; j < 9; ++j) ob[j * HW] = a9[j];
}

// ---------------------------------------------------------------------------
// Pool (2x2 max) + spline expansion: in (BC, H, W) -> SP (BC, 9, H/2, W/2)
// ---------------------------------------------------------------------------
__global__ void pool_spline(const float* __restrict__ in, float* __restrict__ SP,
                            int H, int W, int total) {
    int i = blockIdx.x * blockDim.x + threadIdx.x;
    if (i >= total) return;
    int W2 = W / 2, H2 = H / 2, HW2 = W2 * H2;
    int w = i % W2;
    int h = (i / W2) % H2;
    int bc = i / HW2;
    const float* p = in + ((size_t)bc * H + 2 * h) * W + 2 * w;
    float m = fmaxf(fmaxf(p[0], p[1]), fmaxf(p[W], p[W + 1]));
    float a9[9];
    spline_acts(m, a9);
    float* ob = SP + (size_t)bc * 9 * HW2 + h * W2 + w;
#pragma unroll
    for (int j = 0; j < 9; ++j) ob[j * HW2] = a9[j];
}

// ---------------------------------------------------------------------------
// Plain 2x2 max pool: in (BC, H, W) -> out (BC, H/2, W/2)
// ---------------------------------------------------------------------------
__global__ void maxpool_kernel(const float* __restrict__ in, float* __restrict__ out,
                               int H, int W, int total) {
    int i = blockIdx.x * blockDim.x + threadIdx.x;
    if (i >= total) return;
    int W2 = W / 2, H2 = H / 2, HW2 = W2 * H2;
    int w = i % W2;
    int h = (i / W2) % H2;
    int bc = i / HW2;
    const float* p = in + ((size_t)bc * H + 2 * h) * W + 2 * w;
    out[i] = fmaxf(fmaxf(p[0], p[1]), fmaxf(p[W], p[W + 1]));
}

// ---------------------------------------------------------------------------
// KAN conv over precomputed splines (unchanged from round 2).
// ---------------------------------------------------------------------------
template <int CIN, int COUT, int CO, int H, int W, int EPI>
__global__ __launch_bounds__(256) void conv_kernel(const float* __restrict__ SP,
                                                   const float* __restrict__ wp,
                                                   float* __restrict__ out) {
    constexpr int HW = H * W;
    int n = blockIdx.x * 256 + threadIdx.x;
    const int o0 = blockIdx.y * CO;
    int w = n % W;
    int h = (n / W) % H;
    int b = n / HW;

    float acc[CO];
#pragma unroll
    for (int i = 0; i < CO; ++i) acc[i] = 0.0f;

    const float* spb = SP + (size_t)b * CIN * 9 * HW;
#pragma unroll 1
    for (int cin = 0; cin < CIN; ++cin) {
        const float* spc = spb + cin * 9 * HW;
#pragma unroll
        for (int dh = 0; dh < 3; ++dh) {
            int hh = h + dh - 1;
#pragma unroll
            for (int dw = 0; dw < 3; ++dw) {
                int ww = w + dw - 1;
                bool inb = ((unsigned)hh < (unsigned)H) && ((unsigned)ww < (unsigned)W);
                int off = inb ? hh * W + ww : 0;
                const float* wrow = wp + ((size_t)(cin * 9 + dh * 3 + dw) * 9) * COUT + o0;
#pragma unroll
                for (int j = 0; j < 9; ++j) {
                    float v = spc[j * HW + off];
                    float sj = inb ? v : ZPAD[j];
#pragma unroll
                    for (int co = 0; co < CO; ++co)
                        acc[co] = fmaf(sj, wrow[j * COUT + co], acc[co]);
                }
            }
        }
    }

    int p = h * W + w;
    if (EPI == 0) {
        float* ob = out + ((size_t)b * COUT + o0) * HW + p;
#pragma unroll
        for (int co = 0; co < CO; ++co) ob[(size_t)co * HW] = acc[co];
    } else {
#pragma unroll
        for (int co = 0; co < CO; ++co) {
            float a9[9];
            spline_acts(acc[co], a9);
            float* ob = out + ((size_t)(b * COUT + o0 + co) * 9) * HW + p;
#pragma unroll
            for (int j = 0; j < 9; ++j) ob[j * HW] = a9[j];
        }
    }
}

// ---------------------------------------------------------------------------
// fc_big: C_part[z][m][n] = sum_{k in chunk z} A[m,k]*Wt[n,k]
// 64x64 tile, 256 threads, 4x4 per thread, K_TILE=32, split-K via blockIdx.z.
// LDS is k-major so fragments are float4; A-reads broadcast, W-reads 2-way.
// ---------------------------------------------------------------------------
template <int SPLIT>
__global__ __launch_bounds__(256) void fc_big(const float* __restrict__ A,
                                              const float* __restrict__ Wt,
                                              float* __restrict__ part,
                                              int M, int N, int K) {
    __shared__ float As[32][68];
    __shared__ float Ws[32][68];
    const int tid = threadIdx.x;
    const int tx = tid & 15, ty = tid >> 4;
    const int bm = blockIdx.y * 64, bn = blockIdx.x * 64;
    const int kc = K / SPLIT;
    const int kbeg = blockIdx.z * kc;
    float acc[4][4] = {};
    for (int k0 = kbeg; k0 < kbeg + kc; k0 += 32) {
#pragma unroll
        for (int e = 0; e < 8; ++e) {
            int g = e * 256 + tid;
            int k = g & 31, r = g >> 5;
            As[k][r] = A[(size_t)(bm + r) * K + k0 + k];
            Ws[k][r] = Wt[(size_t)(bn + r) * K + k0 + k];
        }
        __syncthreads();
#pragma unroll
        for (int kk = 0; kk < 32; ++kk) {
            float4 av = *(const float4*)(&As[kk][ty * 4]);
            float4 wv = *(const float4*)(&Ws[kk][tx * 4]);
            acc[0][0] = fmaf(av.x, wv.x, acc[0][0]);
            acc[0][1] = fmaf(av.x, wv.y, acc[0][1]);
            acc[0][2] = fmaf(av.x, wv.z, acc[0][2]);
            acc[0][3] = fmaf(av.x, wv.w, acc[0][3]);
            acc[1][0] = fmaf(av.y, wv.x, acc[1][0]);
            acc[1][1] = fmaf(av.y, wv.y, acc[1][1]);
            acc[1][2] = fmaf(av.y, wv.z, acc[1][2]);
            acc[1][3] = fmaf(av.y, wv.w, acc[1][3]);
            acc[2][0] = fmaf(av.z, wv.x, acc[2][0]);
            acc[2][1] = fmaf(av.z, wv.y, acc[2][1]);
            acc[2][2] = fmaf(av.z, wv.z, acc[2][2]);
            acc[2][3] = fmaf(av.z, wv.w, acc[2][3]);
            acc[3][0] = fmaf(av.w, wv.x, acc[3][0]);
            acc[3][1] = fmaf(av.w, wv.y, acc[3][1]);
            acc[3][2] = fmaf(av.w, wv.z, acc[3][2]);
            acc[3][3] = fmaf(av.w, wv.w, acc[3][3]);
        }
        __syncthreads();
    }
    float* p = part + (size_t)blockIdx.z * M * N;
#pragma unroll
    for (int i = 0; i < 4; ++i) {
        float4 v = make_float4(acc[i][0], acc[i][1], acc[i][2], acc[i][3]);
        *(float4*)&p[(size_t)(bm + ty * 4 + i) * N + (bn + tx * 4)] = v;
    }
}

// Reduce split-K partials + bias + optional relu. SPLIT=4 hardcoded.
__global__ void fc_reduce(const float* __restrict__ part, const float* __restrict__ bias,
                          float* __restrict__ C, int MN, int N, int relu) {
    int i = blockIdx.x * 256 + threadIdx.x;
    if (i >= MN) return;
    float s = part[i] + part[MN + i] + part[2 * MN + i] + part[3 * MN + i] + bias[i % N];
    C[i] = relu ? fmaxf(s, 0.f) : s;
}

// ---------------------------------------------------------------------------
// fc3: M=128, N=10, K=1024. One wave per output element; float4 loads + shuffle.
// ---------------------------------------------------------------------------
__global__ __launch_bounds__(256) void fc3_kernel(const float* __restrict__ A,
                                                  const float* __restrict__ Wt,
                                                  const float* __restrict__ bias,
                                                  float* __restrict__ C) {
    int gid = blockIdx.x * 256 + threadIdx.x;
    int wid = gid >> 6;  // 0..1279
    int lane = gid & 63;
    int m = wid / 10, n = wid - m * 10;
    const float4* a = (const float4*)(A + (size_t)m * 1024);
    const float4* w = (const float4*)(Wt + (size_t)n * 1024);
    float s = 0.f;
#pragma unroll
    for (int it = 0; it < 4; ++it) {
        float4 av = a[it * 64 + lane];
        float4 wv = w[it * 64 + lane];
        s += av.x * wv.x + av.y * wv.y + av.z * wv.z + av.w * wv.w;
    }
#pragma unroll
    for (int off = 32; off; off >>= 1) s += __shfl_xor(s, off);
    if (lane == 0) C[wid] = s + bias[n];
}

// ---------------------------------------------------------------------------
extern "C" void kernel_launch(void* const* d_in, const int* in_sizes, int n_in,
                              void* d_out, int out_size, void* d_ws, size_t ws_size,
                              hipStream_t stream) {
    const float* x   = (const float*)d_in[0];
    const float* bw1 = (const float*)d_in[1];
    const float* sw1 = (const float*)d_in[2];
    const float* sc1 = (const float*)d_in[3];
    const float* bw2 = (const float*)d_in[4];
    const float* sw2 = (const float*)d_in[5];
    const float* sc2 = (const float*)d_in[6];
    const float* bw3 = (const float*)d_in[7];
    const float* sw3 = (const float*)d_in[8];
    const float* sc3 = (const float*)d_in[9];
    const float* bw4 = (const float*)d_in[10];
    const float* sw4 = (const float*)d_in[11];
    const float* sc4 = (const float*)d_in[12];
    const float* w1  = (const float*)d_in[13];
    const float* b1  = (const float*)d_in[14];
    const float* w2  = (const float*)d_in[15];
    const float* b2  = (const float*)d_in[16];
    const float* w3  = (const float*)d_in[17];
    const float* b3  = (const float*)d_in[18];

    float* ws  = (float*)d_ws;
    float* wp1 = ws;           // 27*9*4   @ [0,972)
    float* wp2 = ws + 972;     // 36*9*8   @ [972,3564)
    float* wp3 = ws + 3564;    // 72*9*16  @ [3564,13932)
    float* wp4 = ws + 13932;   // 144*9*32 @ [13932,55404)
    float* base = ws + 65536;
    // liveness-packed activation buffers (floats from base):
    float* SP1    = base;              // [0, 3538944)        (B,3,9,32,32)
    float* SP2    = base + 3538944;    // [3538944, 8257536)  (B,4,9,32,32)
    float* out2   = base;              // [0, 1048576)        over dead SP1
    float* SP3    = base + 1048576;    // [1048576, 3407872)  (B,8,9,16,16)
    float* SP4    = base + 3407872;    // [3407872, 8126464)  (B,16,9,16,16)
    float* out4   = base;              // [0, 1048576)        over dead out2
    float* pooled = base + 1048576;    // [1048576, 1310720)  (B,2048)
    float* part1  = base + 1310720;    // [1310720, 2359296)  4x(128,2048)
    float* fc1o   = base + 2359296;    // [2359296, 2621440)
    float* part2  = base + 2621440;    // [2621440, 3145728)  4x(128,1024)
    float* fc2o   = base + 3145728;    // [3145728, 3276800)
    // peak = (65536 + 8257536) * 4B = 33.3 MB

    pack_all<<<(55404 + 255) / 256, 256, 0, stream>>>(bw1, sw1, sc1, bw2, sw2, sc2,
                                                      bw3, sw3, sc3, bw4, sw4, sc4, ws);

    // spline of input x: (128*3, 1024) -> SP1
    spline_expand<<<1536, 256, 0, stream>>>(x, SP1, 1024, 393216);
    // conv1: SP1 -> SP2 (fused spline epilogue)
    conv_kernel<3, 4, 4, 32, 32, 1><<<dim3(512, 1), 256, 0, stream>>>(SP1, wp1, SP2);
    // conv2: SP2 -> out2 raw
    conv_kernel<4, 8, 8, 32, 32, 0><<<dim3(512, 1), 256, 0, stream>>>(SP2, wp2, out2);
    // pool1 + spline: out2 (128*8,32,32) -> SP3
    pool_spline<<<1024, 256, 0, stream>>>(out2, SP3, 32, 32, 262144);
    // conv3: SP3 -> SP4 (fused spline), 2 groups of 8
    conv_kernel<8, 16, 8, 16, 16, 1><<<dim3(128, 2), 256, 0, stream>>>(SP3, wp3, SP4);
    // conv4: SP4 -> out4 raw, 4 groups of 8
    conv_kernel<16, 32, 8, 16, 16, 0><<<dim3(128, 4), 256, 0, stream>>>(SP4, wp4, out4);
    // pool2: out4 (128*32,16,16) -> pooled (B,2048)
    maxpool_kernel<<<1024, 256, 0, stream>>>(out4, pooled, 16, 16, 262144);
    // fc1: relu(pooled @ w1.T + b1)
    fc_big<4><<<dim3(32, 2, 4), 256, 0, stream>>>(pooled, w1, part1, 128, 2048, 2048);
    fc_reduce<<<1024, 256, 0, stream>>>(part1, b1, fc1o, 262144, 2048, 1);
    // fc2: relu(fc1o @ w2.T + b2)
    fc_big<4><<<dim3(16, 2, 4), 256, 0, stream>>>(fc1o, w2, part2, 128, 1024, 2048);
    fc_reduce<<<512, 256, 0, stream>>>(part2, b2, fc2o, 131072, 1024, 1);
    // fc3
    fc3_kernel<<<320, 256, 0, stream>>>(fc2o, w3, b3, (float*)d_out);
}